// Round 7
// baseline (382.777 us; speedup 1.0000x reference)
//
#include <hip/hip_runtime.h>

// Problem constants
constexpr int kH  = 8;     // heads
constexpr int kD  = 16;    // dim per head
constexpr int kHD = 128;   // H*D
constexpr int kN  = 32;    // neighbors
constexpr int kE  = 32;    // edge feature dim
constexpr int kD0 = 128;   // feats0 channels
constexpr int kD1 = 64;    // feats1 channels

constexpr float SCALE0   = 0.25f;                 // 1/sqrt(16)
constexpr float SCALE1   = 0.14433756729740643f;  // 1/sqrt(48)
constexpr float SHARED_S = 0.70710678118654752f;  // sqrt(0.5)
constexpr float NEGV     = -1e9f;

// ---------------------------------------------------------------------------
// Fully fused SE3 attention, 1 position per block, 2048 blocks.
// vs R5: the early-issued cross-phase k-batch is REMOVED (it spilled: 64 VGPR
// of kv held across Phase A under a 64-reg budget -> 55 MB scratch writes).
// B1 loads issue inside B1 where they're consumed (standalone k2 proved this
// pattern runs at 48 VGPR, no spill). kPos=1 keeps LDS at ~18.4 KB and
// __launch_bounds__(256,8) pins VGPR<=64 -> 8 blocks/CU resident (R3 was
// grid-capped at 4). More resident blocks = more phase diversity: one block's
// HBM k/v streams overlap another's L2 W-GEMM and LDS softmax.
// ---------------------------------------------------------------------------
__global__ __launch_bounds__(256, 8) void se3_fused(
    const float* __restrict__ q0, const float* __restrict__ q1,
    const float* __restrict__ k0, const float* __restrict__ k1,
    const float* __restrict__ v0, const float* __restrict__ v1,
    const float* __restrict__ feats0, const float* __restrict__ feats1,
    const float* __restrict__ edges,
    const float* __restrict__ Wskv0, const float* __restrict__ Wskv1,
    const float* __restrict__ Wbias,
    const float* __restrict__ sbias, const float* __restrict__ nbias,
    const float* __restrict__ nk0, const float* __restrict__ nk1,
    const float* __restrict__ nv0, const float* __restrict__ nv1,
    const float* __restrict__ hw1,
    const float* __restrict__ Wout0, const float* __restrict__ Wout1,
    const int* __restrict__ nmask,
    float* __restrict__ out, int n_total)
{
  const int i = blockIdx.x;
  const int t = threadIdx.x;
  const int q4 = t & 3;        // quad lane
  const int qg = t >> 2;       // quad group 0..63
  const int hB = qg & 7;       // B1 head
  const int jl = qg >> 3;      // B1 j-lane 0..7

  __shared__ __align__(16) float f0s[kD0];          // 128
  __shared__ __align__(16) float f1s[kD1 * 3];      // 192
  __shared__ __align__(16) float q0s[kHD];          // 128
  __shared__ __align__(16) float q1s[kHD * 3];      // 384
  __shared__ float edg[kN * (kE + 1)];              // 1056
  __shared__ float wbs[kH * kE];                    // 256 [h][e]
  __shared__ float w1s[kH];
  __shared__ int   nmL[kN];
  __shared__ float sk0[kHD];                        // 128
  __shared__ __align__(16) float sk1[kHD * 3];      // 384
  __shared__ __align__(16) float sv0[kHD];          // 128
  __shared__ __align__(16) float sv1[kHD * 3];      // 384
  __shared__ float sc[kH][36];                      // 288 (34 used)
  __shared__ __align__(16) float o0p[2][kHD];       // 256 partials
  __shared__ __align__(16) float o1p[2][kHD * 3];   // 768 partials

  // ---------------- Phase 0: stage (direct load->LDS) ----------------
  if (t < 32) {
    ((float4*)f0s)[t] = ((const float4*)(feats0 + (size_t)i * kD0))[t];
  } else if (t < 80) {
    ((float4*)f1s)[t - 32] = ((const float4*)(feats1 + (size_t)i * kD1 * 3))[t - 32];
  } else if (t < 112) {
    ((float4*)q0s)[t - 80] = ((const float4*)(q0 + (size_t)i * kHD))[t - 80];
  } else if (t < 208) {
    ((float4*)q1s)[t - 112] = ((const float4*)(q1 + (size_t)i * kHD * 3))[t - 112];
  }
  { float4 ev = ((const float4*)(edges + (size_t)i * kN * kE))[t];
    int j = t >> 3, e4 = (t & 7) * 4;
    float* dst = &edg[j * 33 + e4];
    dst[0] = ev.x; dst[1] = ev.y; dst[2] = ev.z; dst[3] = ev.w; }
  wbs[t] = Wbias[t];
  if (t < kN) nmL[t] = nmask[(size_t)i * kN + t];
  if (t < kH) w1s[t] = log1pf(expf(hw1[t]));
  __syncthreads();

  // ---------------- Phase A: selfKV (quad-cooperative W rows) ----------------
  #pragma unroll
  for (int pass = 0; pass < 4; ++pass) {
    const int r = qg + 64 * pass;          // W row 0..255
    const float4* w0r = (const float4*)(Wskv0 + (size_t)r * kD0);
    float a0 = 0.f;
    #pragma unroll
    for (int g = 0; g < 8; ++g) {
      float4 w = w0r[q4 + 4 * g]; int c = (q4 + 4 * g) * 4;
      a0 += w.x * f0s[c] + w.y * f0s[c + 1]
          + w.z * f0s[c + 2] + w.w * f0s[c + 3];
    }
    const float4* w1r = (const float4*)(Wskv1 + (size_t)r * kD1);
    float a1[3] = {};
    #pragma unroll
    for (int g = 0; g < 4; ++g) {
      float4 w = w1r[q4 + 4 * g]; int c = (q4 + 4 * g) * 4;
      float wvv[4] = {w.x, w.y, w.z, w.w};
      #pragma unroll
      for (int k = 0; k < 4; ++k) {
        const float* fp = &f1s[(c + k) * 3];
        a1[0] += wvv[k] * fp[0];
        a1[1] += wvv[k] * fp[1];
        a1[2] += wvv[k] * fp[2];
      }
    }
    a0 += __shfl_xor(a0, 1); a0 += __shfl_xor(a0, 2);
    #pragma unroll
    for (int c = 0; c < 3; ++c) {
      a1[c] += __shfl_xor(a1[c], 1);
      a1[c] += __shfl_xor(a1[c], 2);
    }
    if (q4 == 0) {
      if (r < kHD) {
        sk0[r] = a0;
        sk1[r * 3 + 0] = a1[0]; sk1[r * 3 + 1] = a1[1]; sk1[r * 3 + 2] = a1[2];
      } else {
        const int o = r - kHD;
        sv0[o] = a0;
        sv1[o * 3 + 0] = a1[0]; sv1[o * 3 + 1] = a1[1]; sv1[o * 3 + 2] = a1[2];
      }
    }
  }
  __syncthreads();

  // ---------------- Phase B0: null/self scores (t<16) ----------------
  if (t < 16) {
    const int h = t & 7;
    const bool is_self = t >= 8;
    float s0 = 0.f, s1 = 0.f, bias;
    if (is_self) {
      #pragma unroll
      for (int d = 0; d < kD; ++d) s0 += q0s[h * kD + d] * sk0[h * kD + d];
      #pragma unroll
      for (int x = 0; x < 48; ++x) s1 += q1s[h * 48 + x] * sk1[h * 48 + x];
      bias = sbias[h];
    } else {
      #pragma unroll
      for (int d = 0; d < kD; ++d) s0 += q0s[h * kD + d] * nk0[h * kD + d];
      #pragma unroll
      for (int x = 0; x < 48; ++x) s1 += q1s[h * 48 + x] * nk1[h * 48 + x];
      bias = nbias[h];
    }
    sc[h][is_self ? 1 : 0] =
        (s0 * SCALE0 + bias + s1 * SCALE1 * w1s[h]) * SHARED_S;
  }

  // ---------------- Phase B1: neighbor scores (quad-coalesced k loads) -------
  {
    const float w1h = w1s[hB];
    float wbf[8];
    #pragma unroll
    for (int e = 0; e < 8; ++e) wbf[e] = wbs[hB * kE + q4 * 8 + e];
    const float4 q0f = *((const float4*)(q0s + hB * kD) + q4);
    float4 q1f[3];
    #pragma unroll
    for (int pc = 0; pc < 3; ++pc)
      q1f[pc] = *((const float4*)(q1s + hB * 48 + pc * 16) + q4);

    const float* k0base = k0 + (size_t)i * kN * kHD + hB * kD + q4 * 4;
    const float* k1base = k1 + (size_t)i * kN * kHD * 3 + hB * 48 + q4 * 4;

    float4 kv0[4];
    float4 kv1[4][3];
    #pragma unroll
    for (int pp = 0; pp < 4; ++pp) {
      const int j = pp * 8 + jl;
      kv0[pp] = *((const float4*)(k0base + (size_t)j * kHD));
      #pragma unroll
      for (int pc = 0; pc < 3; ++pc)
        kv1[pp][pc] = *((const float4*)(k1base + (size_t)j * kHD * 3 + pc * 16));
    }

    #pragma unroll
    for (int pp = 0; pp < 4; ++pp) {
      const int j = pp * 8 + jl;
      float s0 = kv0[pp].x * q0f.x + kv0[pp].y * q0f.y
               + kv0[pp].z * q0f.z + kv0[pp].w * q0f.w;
      float s1 = 0.f;
      #pragma unroll
      for (int pc = 0; pc < 3; ++pc)
        s1 += kv1[pp][pc].x * q1f[pc].x + kv1[pp][pc].y * q1f[pc].y
            + kv1[pp][pc].z * q1f[pc].z + kv1[pp][pc].w * q1f[pc].w;
      float bias = 0.f;
      #pragma unroll
      for (int e = 0; e < 8; ++e) bias += edg[j * 33 + q4 * 8 + e] * wbf[e];

      float part = s0 * SCALE0 + bias + s1 * SCALE1 * w1h;
      part += __shfl_xor(part, 1);
      part += __shfl_xor(part, 2);
      if (q4 == 0) sc[hB][2 + j] = nmL[j] ? part * SHARED_S : NEGV;
    }
  }
  __syncthreads();

  // ---------------- Phase C: softmax (8 rows x 16 lanes) ----------------
  if (t < 128) {
    const int h = t >> 4, l = t & 15;
    float* rp = sc[h];
    float va = rp[2 + l], vb = rp[2 + l + 16];
    float mx = fmaxf(va, vb);
    #pragma unroll
    for (int off = 8; off > 0; off >>= 1) mx = fmaxf(mx, __shfl_xor(mx, off));
    float e0v = rp[0], e1v = rp[1];
    mx = fmaxf(mx, fmaxf(e0v, e1v));
    float ea = __expf(va - mx), eb = __expf(vb - mx);
    float sum = ea + eb;
    #pragma unroll
    for (int off = 8; off > 0; off >>= 1) sum += __shfl_xor(sum, off);
    float ee0 = __expf(e0v - mx), ee1 = __expf(e1v - mx);
    float inv = 1.f / (sum + ee0 + ee1);
    rp[2 + l] = ea * inv;
    rp[2 + l + 16] = eb * inv;
    if (l == 0) rp[0] = ee0 * inv;
    if (l == 1) rp[1] = ee1 * inv;
  }
  __syncthreads();

  // ---------------- Phase D: attn*V, half-split (all 256 threads) ----------
  {
    const int halfD = t >> 7;        // 0: rows 0..15 (+null/self), 1: rows 16..31
    const int s = t & 127;
    float4 acc = {0.f, 0.f, 0.f, 0.f};
    if (s < 32) {
      const int h = s >> 2;
      const float* at = sc[h];
      if (halfD == 0) {
        float4 nv = ((const float4*)nv0)[s];
        float4 sv = ((const float4*)sv0)[s];
        acc.x = at[0] * nv.x + at[1] * sv.x;
        acc.y = at[0] * nv.y + at[1] * sv.y;
        acc.z = at[0] * nv.z + at[1] * sv.z;
        acc.w = at[0] * nv.w + at[1] * sv.w;
      }
      const float4* vp = (const float4*)(v0 + (size_t)i * kN * kHD) + s;
      float4 vbuf[8];
      #pragma unroll
      for (int gg = 0; gg < 2; ++gg) {
        const int g = halfD * 2 + gg;
        #pragma unroll
        for (int r = 0; r < 8; ++r) vbuf[r] = vp[(g * 8 + r) * 32];
        #pragma unroll
        for (int r = 0; r < 8; ++r) {
          float a = at[2 + g * 8 + r];
          acc.x += a * vbuf[r].x; acc.y += a * vbuf[r].y;
          acc.z += a * vbuf[r].z; acc.w += a * vbuf[r].w;
        }
      }
      ((float4*)o0p[halfD])[s] = acc;
    } else {
      const int s1 = s - 32;           // 0..95 (head-aligned: 48%4==0)
      const int h = s1 / 12;
      const float* at = sc[h];
      if (halfD == 0) {
        float4 nv = ((const float4*)nv1)[s1];
        float4 sv = ((const float4*)sv1)[s1];
        acc.x = at[0] * nv.x + at[1] * sv.x;
        acc.y = at[0] * nv.y + at[1] * sv.y;
        acc.z = at[0] * nv.z + at[1] * sv.z;
        acc.w = at[0] * nv.w + at[1] * sv.w;
      }
      const float4* vp = (const float4*)(v1 + (size_t)i * kN * kHD * 3) + s1;
      float4 vbuf[8];
      #pragma unroll
      for (int gg = 0; gg < 2; ++gg) {
        const int g = halfD * 2 + gg;
        #pragma unroll
        for (int r = 0; r < 8; ++r) vbuf[r] = vp[(g * 8 + r) * 96];
        #pragma unroll
        for (int r = 0; r < 8; ++r) {
          float a = at[2 + g * 8 + r];
          acc.x += a * vbuf[r].x; acc.y += a * vbuf[r].y;
          acc.z += a * vbuf[r].z; acc.w += a * vbuf[r].w;
        }
      }
      ((float4*)o1p[halfD])[s1] = acc;
    }
  }
  __syncthreads();

  // combine the two halves (t<128: 32 o0 chunks + 96 o1 chunks)
  if (t < 128) {
    if (t < 32) {
      float4 a = ((float4*)o0p[0])[t], b = ((float4*)o0p[1])[t];
      a.x += b.x; a.y += b.y; a.z += b.z; a.w += b.w;
      ((float4*)o0p[0])[t] = a;
    } else {
      const int s1 = t - 32;
      float4 a = ((float4*)o1p[0])[s1], b = ((float4*)o1p[1])[s1];
      a.x += b.x; a.y += b.y; a.z += b.z; a.w += b.w;
      ((float4*)o1p[0])[s1] = a;
    }
  }
  __syncthreads();

  // ---------------- Phase E: output projections (quad-cooperative) ----------
  #pragma unroll
  for (int pass = 0; pass < 5; ++pass) {
    const int u = qg + 64 * pass;          // 0..319 (wave-uniform branch)
    if (u < 128) {
      const float4* wr = (const float4*)(Wout0 + (size_t)u * kHD);
      float a = 0.f;
      #pragma unroll
      for (int g = 0; g < 8; ++g) {
        float4 w = wr[q4 + 4 * g]; int c = (q4 + 4 * g) * 4;
        a += w.x * o0p[0][c] + w.y * o0p[0][c + 1]
           + w.z * o0p[0][c + 2] + w.w * o0p[0][c + 3];
      }
      a += __shfl_xor(a, 1); a += __shfl_xor(a, 2);
      if (q4 == 0) out[(size_t)i * kHD + u] = a;
    } else {
      const int v2 = u - 128, o = v2 / 3, m = v2 - o * 3;
      const float4* wr = (const float4*)(Wout1 + (size_t)o * kHD);
      float a = 0.f;
      #pragma unroll
      for (int g = 0; g < 8; ++g) {
        float4 w = wr[q4 + 4 * g]; int c = (q4 + 4 * g) * 4;
        a += w.x * o1p[0][(c + 0) * 3 + m] + w.y * o1p[0][(c + 1) * 3 + m]
           + w.z * o1p[0][(c + 2) * 3 + m] + w.w * o1p[0][(c + 3) * 3 + m];
      }
      a += __shfl_xor(a, 1); a += __shfl_xor(a, 2);
      if (q4 == 0)
        out[(size_t)n_total * kHD + (size_t)i * 192 + v2] = a;
    }
  }
}

extern "C" void kernel_launch(void* const* d_in, const int* in_sizes, int n_in,
                              void* d_out, int out_size, void* d_ws, size_t ws_size,
                              hipStream_t stream) {
  const int n = in_sizes[0] / kHD;  // 2048
  const float* q0     = (const float*)d_in[0];
  const float* k0     = (const float*)d_in[1];
  const float* v0     = (const float*)d_in[2];
  const float* q1     = (const float*)d_in[3];
  const float* k1     = (const float*)d_in[4];
  const float* v1     = (const float*)d_in[5];
  const float* feats0 = (const float*)d_in[6];
  const float* feats1 = (const float*)d_in[7];
  const float* edges  = (const float*)d_in[8];
  const float* Wskv0  = (const float*)d_in[9];
  const float* Wskv1  = (const float*)d_in[10];
  const float* Wbias  = (const float*)d_in[11];
  const float* sbias  = (const float*)d_in[12];
  const float* nbias  = (const float*)d_in[13];
  const float* nk0    = (const float*)d_in[14];
  const float* nv0    = (const float*)d_in[15];
  const float* nk1    = (const float*)d_in[16];
  const float* nv1    = (const float*)d_in[17];
  const float* hw1    = (const float*)d_in[18];
  const float* Wout0  = (const float*)d_in[19];
  const float* Wout1  = (const float*)d_in[20];
  const int*   nmask  = (const int*)d_in[21];

  se3_fused<<<n, 256, 0, stream>>>(
      q0, q1, k0, k1, v0, v1, feats0, feats1, edges,
      Wskv0, Wskv1, Wbias, sbias, nbias, nk0, nk1, nv0, nv1, hw1,
      Wout0, Wout1, nmask, (float*)d_out, n);
}

// Round 8
// 318.720 us; speedup vs baseline: 1.2010x; 1.2010x over previous
//
#include <hip/hip_runtime.h>

// Problem constants
constexpr int kH  = 8;     // heads
constexpr int kD  = 16;    // dim per head
constexpr int kHD = 128;   // H*D
constexpr int kN  = 32;    // neighbors
constexpr int kE  = 32;    // edge feature dim
constexpr int kD0 = 128;   // feats0 channels
constexpr int kD1 = 64;    // feats1 channels

constexpr float SCALE0   = 0.25f;                 // 1/sqrt(16)
constexpr float SCALE1   = 0.14433756729740643f;  // 1/sqrt(48)
constexpr float SHARED_S = 0.70710678118654752f;  // sqrt(0.5)
constexpr float NEGV     = -1e9f;

// ---------------------------------------------------------------------------
// Fully fused SE3 attention, 1 position per block, 2048 blocks.
// R7: register-pressure diet targeting NATURAL VGPR<=64 (R6 proved 8 blocks/CU
// works but forcing via launch_bounds(256,8) crushed to 32 VGPR + 130MB spill):
//  - edge-bias dot hoisted out of B1 into its own pass (biasL[8][32] in LDS)
//  - B1 k-batch chunked 16->2x8 float4 (32-reg peak), sched_barrier between
//  - launch_bounds(256,4): cap 128, no forced spill; allocator free to hit 64
// ---------------------------------------------------------------------------
__global__ __launch_bounds__(256, 4) void se3_fused(
    const float* __restrict__ q0, const float* __restrict__ q1,
    const float* __restrict__ k0, const float* __restrict__ k1,
    const float* __restrict__ v0, const float* __restrict__ v1,
    const float* __restrict__ feats0, const float* __restrict__ feats1,
    const float* __restrict__ edges,
    const float* __restrict__ Wskv0, const float* __restrict__ Wskv1,
    const float* __restrict__ Wbias,
    const float* __restrict__ sbias, const float* __restrict__ nbias,
    const float* __restrict__ nk0, const float* __restrict__ nk1,
    const float* __restrict__ nv0, const float* __restrict__ nv1,
    const float* __restrict__ hw1,
    const float* __restrict__ Wout0, const float* __restrict__ Wout1,
    const int* __restrict__ nmask,
    float* __restrict__ out, int n_total)
{
  const int i = blockIdx.x;
  const int t = threadIdx.x;
  const int q4 = t & 3;        // quad lane
  const int qg = t >> 2;       // quad group 0..63
  const int hB = qg & 7;       // B1 head
  const int jl = qg >> 3;      // B1 j-lane 0..7

  __shared__ __align__(16) float f0s[kD0];          // 128
  __shared__ __align__(16) float f1s[kD1 * 3];      // 192
  __shared__ __align__(16) float q0s[kHD];          // 128
  __shared__ __align__(16) float q1s[kHD * 3];      // 384
  __shared__ float edg[kN * (kE + 1)];              // 1056
  __shared__ float wbs[kH * kE];                    // 256 [h][e]
  __shared__ float w1s[kH];
  __shared__ int   nmL[kN];
  __shared__ float biasL[kH][kN];                   // 256 precomputed pair-bias
  __shared__ float sk0[kHD];                        // 128
  __shared__ __align__(16) float sk1[kHD * 3];      // 384
  __shared__ __align__(16) float sv0[kHD];          // 128
  __shared__ __align__(16) float sv1[kHD * 3];      // 384
  __shared__ float sc[kH][36];                      // 288 (34 used)
  __shared__ __align__(16) float o0p[2][kHD];       // 256 partials
  __shared__ __align__(16) float o1p[2][kHD * 3];   // 768 partials

  // ---------------- Phase 0: stage (direct load->LDS) ----------------
  if (t < 32) {
    ((float4*)f0s)[t] = ((const float4*)(feats0 + (size_t)i * kD0))[t];
  } else if (t < 80) {
    ((float4*)f1s)[t - 32] = ((const float4*)(feats1 + (size_t)i * kD1 * 3))[t - 32];
  } else if (t < 112) {
    ((float4*)q0s)[t - 80] = ((const float4*)(q0 + (size_t)i * kHD))[t - 80];
  } else if (t < 208) {
    ((float4*)q1s)[t - 112] = ((const float4*)(q1 + (size_t)i * kHD * 3))[t - 112];
  }
  { float4 ev = ((const float4*)(edges + (size_t)i * kN * kE))[t];
    int j = t >> 3, e4 = (t & 7) * 4;
    float* dst = &edg[j * 33 + e4];
    dst[0] = ev.x; dst[1] = ev.y; dst[2] = ev.z; dst[3] = ev.w; }
  wbs[t] = Wbias[t];
  if (t < kN) nmL[t] = nmask[(size_t)i * kN + t];
  if (t < kH) w1s[t] = log1pf(expf(hw1[t]));
  __syncthreads();

  // ---------------- Phase A: selfKV (quad-cooperative W rows) ----------------
  #pragma unroll
  for (int pass = 0; pass < 4; ++pass) {
    const int r = qg + 64 * pass;          // W row 0..255
    const float4* w0r = (const float4*)(Wskv0 + (size_t)r * kD0);
    float a0 = 0.f;
    #pragma unroll
    for (int g = 0; g < 8; ++g) {
      float4 w = w0r[q4 + 4 * g]; int c = (q4 + 4 * g) * 4;
      a0 += w.x * f0s[c] + w.y * f0s[c + 1]
          + w.z * f0s[c + 2] + w.w * f0s[c + 3];
    }
    const float4* w1r = (const float4*)(Wskv1 + (size_t)r * kD1);
    float a1[3] = {};
    #pragma unroll
    for (int g = 0; g < 4; ++g) {
      float4 w = w1r[q4 + 4 * g]; int c = (q4 + 4 * g) * 4;
      float wvv[4] = {w.x, w.y, w.z, w.w};
      #pragma unroll
      for (int k = 0; k < 4; ++k) {
        const float* fp = &f1s[(c + k) * 3];
        a1[0] += wvv[k] * fp[0];
        a1[1] += wvv[k] * fp[1];
        a1[2] += wvv[k] * fp[2];
      }
    }
    a0 += __shfl_xor(a0, 1); a0 += __shfl_xor(a0, 2);
    #pragma unroll
    for (int c = 0; c < 3; ++c) {
      a1[c] += __shfl_xor(a1[c], 1);
      a1[c] += __shfl_xor(a1[c], 2);
    }
    if (q4 == 0) {
      if (r < kHD) {
        sk0[r] = a0;
        sk1[r * 3 + 0] = a1[0]; sk1[r * 3 + 1] = a1[1]; sk1[r * 3 + 2] = a1[2];
      } else {
        const int o = r - kHD;
        sv0[o] = a0;
        sv1[o * 3 + 0] = a1[0]; sv1[o * 3 + 1] = a1[1]; sv1[o * 3 + 2] = a1[2];
      }
    }
  }

  // ---------------- Phase A2: pair-bias precompute (1 value/thread) ---------
  // biasL[h][j] = dot32(edg[j], wbs[h]); pure LDS, overlaps Phase A's tail.
  {
    const int h = t >> 5, j = t & 31;
    float b = 0.f;
    #pragma unroll
    for (int e = 0; e < kE; ++e) b += edg[j * 33 + e] * wbs[h * kE + e];
    biasL[h][j] = b;
  }
  __syncthreads();

  // ---------------- Phase B0: null/self scores (t<16) ----------------
  if (t < 16) {
    const int h = t & 7;
    const bool is_self = t >= 8;
    float s0 = 0.f, s1 = 0.f, bias;
    if (is_self) {
      #pragma unroll
      for (int d = 0; d < kD; ++d) s0 += q0s[h * kD + d] * sk0[h * kD + d];
      #pragma unroll
      for (int x = 0; x < 48; ++x) s1 += q1s[h * 48 + x] * sk1[h * 48 + x];
      bias = sbias[h];
    } else {
      #pragma unroll
      for (int d = 0; d < kD; ++d) s0 += q0s[h * kD + d] * nk0[h * kD + d];
      #pragma unroll
      for (int x = 0; x < 48; ++x) s1 += q1s[h * 48 + x] * nk1[h * 48 + x];
      bias = nbias[h];
    }
    sc[h][is_self ? 1 : 0] =
        (s0 * SCALE0 + bias + s1 * SCALE1 * w1s[h]) * SHARED_S;
  }

  // ---------------- Phase B1: neighbor scores (2x8-float4 chunks) ----------
  {
    const float w1h = w1s[hB];
    const float4 q0f = *((const float4*)(q0s + hB * kD) + q4);
    float4 q1f[3];
    #pragma unroll
    for (int pc = 0; pc < 3; ++pc)
      q1f[pc] = *((const float4*)(q1s + hB * 48 + pc * 16) + q4);

    const float* k0base = k0 + (size_t)i * kN * kHD + hB * kD + q4 * 4;
    const float* k1base = k1 + (size_t)i * kN * kHD * 3 + hB * 48 + q4 * 4;

    #pragma unroll
    for (int half = 0; half < 2; ++half) {
      float4 kv0[2];
      float4 kv1[2][3];
      #pragma unroll
      for (int pp = 0; pp < 2; ++pp) {
        const int j = (half * 2 + pp) * 8 + jl;
        kv0[pp] = *((const float4*)(k0base + (size_t)j * kHD));
        #pragma unroll
        for (int pc = 0; pc < 3; ++pc)
          kv1[pp][pc] = *((const float4*)(k1base + (size_t)j * kHD * 3 + pc * 16));
      }
      #pragma unroll
      for (int pp = 0; pp < 2; ++pp) {
        const int j = (half * 2 + pp) * 8 + jl;
        float s0 = kv0[pp].x * q0f.x + kv0[pp].y * q0f.y
                 + kv0[pp].z * q0f.z + kv0[pp].w * q0f.w;
        float s1 = 0.f;
        #pragma unroll
        for (int pc = 0; pc < 3; ++pc)
          s1 += kv1[pp][pc].x * q1f[pc].x + kv1[pp][pc].y * q1f[pc].y
              + kv1[pp][pc].z * q1f[pc].z + kv1[pp][pc].w * q1f[pc].w;
        float part = s0 * SCALE0 + s1 * SCALE1 * w1h;
        part += __shfl_xor(part, 1);
        part += __shfl_xor(part, 2);
        if (q4 == 0)
          sc[hB][2 + j] = nmL[j] ? (part + biasL[hB][j]) * SHARED_S : NEGV;
      }
      __builtin_amdgcn_sched_barrier(0);   // keep chunks separate (reg cap)
    }
  }
  __syncthreads();

  // ---------------- Phase C: softmax (8 rows x 16 lanes) ----------------
  if (t < 128) {
    const int h = t >> 4, l = t & 15;
    float* rp = sc[h];
    float va = rp[2 + l], vb = rp[2 + l + 16];
    float mx = fmaxf(va, vb);
    #pragma unroll
    for (int off = 8; off > 0; off >>= 1) mx = fmaxf(mx, __shfl_xor(mx, off));
    float e0v = rp[0], e1v = rp[1];
    mx = fmaxf(mx, fmaxf(e0v, e1v));
    float ea = __expf(va - mx), eb = __expf(vb - mx);
    float sum = ea + eb;
    #pragma unroll
    for (int off = 8; off > 0; off >>= 1) sum += __shfl_xor(sum, off);
    float ee0 = __expf(e0v - mx), ee1 = __expf(e1v - mx);
    float inv = 1.f / (sum + ee0 + ee1);
    rp[2 + l] = ea * inv;
    rp[2 + l + 16] = eb * inv;
    if (l == 0) rp[0] = ee0 * inv;
    if (l == 1) rp[1] = ee1 * inv;
  }
  __syncthreads();

  // ---------------- Phase D: attn*V, half-split (all 256 threads) ----------
  {
    const int halfD = t >> 7;        // 0: rows 0..15 (+null/self), 1: rows 16..31
    const int s = t & 127;
    float4 acc = {0.f, 0.f, 0.f, 0.f};
    if (s < 32) {
      const int h = s >> 2;
      const float* at = sc[h];
      if (halfD == 0) {
        float4 nv = ((const float4*)nv0)[s];
        float4 sv = ((const float4*)sv0)[s];
        acc.x = at[0] * nv.x + at[1] * sv.x;
        acc.y = at[0] * nv.y + at[1] * sv.y;
        acc.z = at[0] * nv.z + at[1] * sv.z;
        acc.w = at[0] * nv.w + at[1] * sv.w;
      }
      const float4* vp = (const float4*)(v0 + (size_t)i * kN * kHD) + s;
      float4 vbuf[8];
      #pragma unroll
      for (int gg = 0; gg < 2; ++gg) {
        const int g = halfD * 2 + gg;
        #pragma unroll
        for (int r = 0; r < 8; ++r) vbuf[r] = vp[(g * 8 + r) * 32];
        #pragma unroll
        for (int r = 0; r < 8; ++r) {
          float a = at[2 + g * 8 + r];
          acc.x += a * vbuf[r].x; acc.y += a * vbuf[r].y;
          acc.z += a * vbuf[r].z; acc.w += a * vbuf[r].w;
        }
      }
      ((float4*)o0p[halfD])[s] = acc;
    } else {
      const int s1 = s - 32;           // 0..95 (head-aligned: 48%4==0)
      const int h = s1 / 12;
      const float* at = sc[h];
      if (halfD == 0) {
        float4 nv = ((const float4*)nv1)[s1];
        float4 sv = ((const float4*)sv1)[s1];
        acc.x = at[0] * nv.x + at[1] * sv.x;
        acc.y = at[0] * nv.y + at[1] * sv.y;
        acc.z = at[0] * nv.z + at[1] * sv.z;
        acc.w = at[0] * nv.w + at[1] * sv.w;
      }
      const float4* vp = (const float4*)(v1 + (size_t)i * kN * kHD * 3) + s1;
      float4 vbuf[8];
      #pragma unroll
      for (int gg = 0; gg < 2; ++gg) {
        const int g = halfD * 2 + gg;
        #pragma unroll
        for (int r = 0; r < 8; ++r) vbuf[r] = vp[(g * 8 + r) * 96];
        #pragma unroll
        for (int r = 0; r < 8; ++r) {
          float a = at[2 + g * 8 + r];
          acc.x += a * vbuf[r].x; acc.y += a * vbuf[r].y;
          acc.z += a * vbuf[r].z; acc.w += a * vbuf[r].w;
        }
      }
      ((float4*)o1p[halfD])[s1] = acc;
    }
  }
  __syncthreads();

  // combine the two halves (t<128: 32 o0 chunks + 96 o1 chunks)
  if (t < 128) {
    if (t < 32) {
      float4 a = ((float4*)o0p[0])[t], b = ((float4*)o0p[1])[t];
      a.x += b.x; a.y += b.y; a.z += b.z; a.w += b.w;
      ((float4*)o0p[0])[t] = a;
    } else {
      const int s1 = t - 32;
      float4 a = ((float4*)o1p[0])[s1], b = ((float4*)o1p[1])[s1];
      a.x += b.x; a.y += b.y; a.z += b.z; a.w += b.w;
      ((float4*)o1p[0])[s1] = a;
    }
  }
  __syncthreads();

  // ---------------- Phase E: output projections (quad-cooperative) ----------
  #pragma unroll
  for (int pass = 0; pass < 5; ++pass) {
    const int u = qg + 64 * pass;          // 0..319 (wave-uniform branch)
    if (u < 128) {
      const float4* wr = (const float4*)(Wout0 + (size_t)u * kHD);
      float a = 0.f;
      #pragma unroll
      for (int g = 0; g < 8; ++g) {
        float4 w = wr[q4 + 4 * g]; int c = (q4 + 4 * g) * 4;
        a += w.x * o0p[0][c] + w.y * o0p[0][c + 1]
           + w.z * o0p[0][c + 2] + w.w * o0p[0][c + 3];
      }
      a += __shfl_xor(a, 1); a += __shfl_xor(a, 2);
      if (q4 == 0) out[(size_t)i * kHD + u] = a;
    } else {
      const int v2 = u - 128, o = v2 / 3, m = v2 - o * 3;
      const float4* wr = (const float4*)(Wout1 + (size_t)o * kHD);
      float a = 0.f;
      #pragma unroll
      for (int g = 0; g < 8; ++g) {
        float4 w = wr[q4 + 4 * g]; int c = (q4 + 4 * g) * 4;
        a += w.x * o1p[0][(c + 0) * 3 + m] + w.y * o1p[0][(c + 1) * 3 + m]
           + w.z * o1p[0][(c + 2) * 3 + m] + w.w * o1p[0][(c + 3) * 3 + m];
      }
      a += __shfl_xor(a, 1); a += __shfl_xor(a, 2);
      if (q4 == 0)
        out[(size_t)n_total * kHD + (size_t)i * 192 + v2] = a;
    }
  }
}

extern "C" void kernel_launch(void* const* d_in, const int* in_sizes, int n_in,
                              void* d_out, int out_size, void* d_ws, size_t ws_size,
                              hipStream_t stream) {
  const int n = in_sizes[0] / kHD;  // 2048
  const float* q0     = (const float*)d_in[0];
  const float* k0     = (const float*)d_in[1];
  const float* v0     = (const float*)d_in[2];
  const float* q1     = (const float*)d_in[3];
  const float* k1     = (const float*)d_in[4];
  const float* v1     = (const float*)d_in[5];
  const float* feats0 = (const float*)d_in[6];
  const float* feats1 = (const float*)d_in[7];
  const float* edges  = (const float*)d_in[8];
  const float* Wskv0  = (const float*)d_in[9];
  const float* Wskv1  = (const float*)d_in[10];
  const float* Wbias  = (const float*)d_in[11];
  const float* sbias  = (const float*)d_in[12];
  const float* nbias  = (const float*)d_in[13];
  const float* nk0    = (const float*)d_in[14];
  const float* nv0    = (const float*)d_in[15];
  const float* nk1    = (const float*)d_in[16];
  const float* nv1    = (const float*)d_in[17];
  const float* hw1    = (const float*)d_in[18];
  const float* Wout0  = (const float*)d_in[19];
  const float* Wout1  = (const float*)d_in[20];
  const int*   nmask  = (const int*)d_in[21];

  se3_fused<<<n, 256, 0, stream>>>(
      q0, q1, k0, k1, v0, v1, feats0, feats1, edges,
      Wskv0, Wskv1, Wbias, sbias, nbias, nk0, nk1, nv0, nv1, hw1,
      Wout0, Wout1, nmask, (float*)d_out, n);
}